// Round 1
// 9947.412 us; speedup vs baseline: 1.0690x; 1.0690x over previous
//
#include <hip/hip_runtime.h>
#include <hip/hip_fp16.h>

#define B_ 256
#define S_ 512
#define F_ 64
#define H_ 1024
#define O_ 24
#define G_ 4096  // 4*H

typedef _Float16 half_t;
typedef _Float16 h8 __attribute__((ext_vector_type(8)));
typedef float f4 __attribute__((ext_vector_type(4)));

// ---- workspace layout (bytes) ----
#define OFF_H1 ((size_t)0)                                   // 2*B*H halfs (ping-pong)
#define OFF_H2 (OFF_H1 + (size_t)2*B_*H_*2)
#define OFF_C1 (OFF_H2 + (size_t)2*B_*H_*2)                  // B*H f32
#define OFF_C2 (OFF_C1 + (size_t)B_*H_*4)
#define OFF_OP (OFF_C2 + (size_t)B_*H_*4)                    // out_part [32][B][O] f32
#define ZBYTES (OFF_OP + (size_t)32*B_*O_*4)
#define OFF_BIAS0 (ZBYTES)
#define OFF_BIAS1 (OFF_BIAS0 + (size_t)G_*4)
#define OFF_XH    (OFF_BIAS1 + (size_t)G_*4)                 // B*S*F halfs
#define OFF_WIH0  (OFF_XH + (size_t)B_*S_*F_*2)              // packed, G*F halfs
#define OFF_WHH0  (OFF_WIH0 + (size_t)G_*F_*2)               // packed, G*H halfs
#define OFF_WIH1  (OFF_WHH0 + (size_t)G_*H_*2)
#define OFF_WHH1  (OFF_WIH1 + (size_t)G_*H_*2)
#define WS_NEEDED (OFF_WHH1 + (size_t)G_*H_*2)               // ~47.5 MB

__global__ void k_bias(const float* __restrict__ bi0, const float* __restrict__ bh0,
                       const float* __restrict__ bi1, const float* __restrict__ bh1,
                       float* __restrict__ bias0, float* __restrict__ bias1) {
    int i = blockIdx.x * blockDim.x + threadIdx.x;
    if (i < G_) { bias0[i] = bi0[i] + bh0[i]; bias1[i] = bi1[i] + bh1[i]; }
}

__global__ void k_cvt(const float* __restrict__ src, half_t* __restrict__ dst, int n) {
    int i = blockIdx.x * blockDim.x + threadIdx.x;
    int stride = gridDim.x * blockDim.x;
    for (; i < n; i += stride) dst[i] = (half_t)src[i];
}

// Pack W [4H, NC*64] f32 -> fp16 MFMA-fragment order:
// dst h8 index i = (((g*32+ht)*NC + ck)*4 + j)*64 + lane, j = colhalf*2 + kshalf
__global__ void k_pack(const float* __restrict__ src, half_t* __restrict__ dst, int NC) {
    int i = blockIdx.x * blockDim.x + threadIdx.x;
    int total = 32768 * NC;          // 4*32*NC*4*64
    if (i >= total) return;
    int lane = i & 63;
    int j    = (i >> 6) & 3;
    int ck   = (i >> 8) % NC;
    int gh   = i / (256 * NC);       // g*32+ht, 0..127
    int srow = (gh >> 5) * H_ + (gh & 31) * 32 + (j >> 1) * 16 + (lane & 15);
    int scol = ck * 64 + (j & 1) * 32 + (lane >> 4) * 8;
    const float* s = src + (size_t)srow * (NC * 64) + scol;
    h8 v;
    #pragma unroll
    for (int e = 0; e < 8; ++e) v[e] = (half_t)s[e];
    *(h8*)&dst[(size_t)i * 8] = v;
}

// Fused phase kernel (multi-launch; persistent+grid-barrier measured 5x WORSE:
// agent-scope acquire polls invalidate L2 -> 11 GB HBM refetch, R7 counters).
// Phase t = layer0 step t (blocks 256..511) + layer1 step t-1 (blocks 0..255),
// 2 blocks/CU (one l0 + one l1 per CU via n%8-XCD, (n/8)%32-CU round robin).
//
// THIS ROUND (latency-hiding pass, theory: ~7 us of per-phase stalls):
//  1. W pipeline deepened 1 -> 3 chunks ahead (4 rotating register sets;
//     4 divides the 8-step window so set alignment is compile-time).
//  2. A windows software-pipelined: next window's 8 global loads issued
//     BEFORE computing the current window; A LDS double-buffered (2x36864B)
//     so only ONE full-drain __syncthreads per window instead of two.
//  3. Epilogue tail loads hoisted to kernel start: c[] (sole-owner slice)
//     and the fcW t-slice (HBM-cold, ~900cy) prefetched into regs at t0,
//     consumed ~15us later; fcW staged via 3KB LDS overlay for broadcast FC.
__global__ __launch_bounds__(256, 2)
void k_phase(int t,
             const half_t* __restrict__ x_h,
             const half_t* __restrict__ Wih0, const half_t* __restrict__ Whh0,
             const float* __restrict__ bias0, float* __restrict__ c1g, half_t* __restrict__ h1buf,
             const half_t* __restrict__ Wih1, const half_t* __restrict__ Whh1,
             const float* __restrict__ bias1, float* __restrict__ c2g, half_t* __restrict__ h2buf,
             const float* __restrict__ fcW, float* __restrict__ out_part)
{
    // Double-buffered 8-chunk A windows: 2 x [8][32*72] halfs = 73728 B
    // (2 blocks/CU -> 147456 B/CU <= 160 KiB). Epilogue LDS unioned on buf0.
    __shared__ __align__(16) char smraw[73728];
    half_t* A_s    = (half_t*)smraw;
    float*  gate_s = (float*)smraw;                  // [4][32*33] = 16896 B
    float*  h_s    = (float*)(smraw + 16896);        // [32*33]    =  4224 B
    float*  fcw_s  = (float*)(smraw + 21120);        // [24*32]    =  3072 B

    const int n  = blockIdx.x;
    const bool l1 = (n < 256);
    const int m  = l1 ? n : n - 256;
    const int ht = (m & 7) + 8 * ((m >> 3) & 3);   // ht % 8 == linear_id % 8 (XCD-resident W)
    const int bt = (m >> 5) & 7;

    int tt; const half_t* xb; int ldx, cx; const half_t* Wih;
    const half_t* Whh; const float* bias; float* c; half_t* hn_out; const half_t* hp;
    if (l1) {
        if (t == 0) return;
        tt = t - 1;
        xb  = h1buf + (size_t)(tt & 1) * B_ * H_;  ldx = H_;      cx = 16;
        Wih = Wih1;  Whh = Whh1;  bias = bias1;  c = c2g;
        hp     = h2buf + (size_t)((tt - 1) & 1) * B_ * H_;
        hn_out = h2buf + (size_t)(tt & 1) * B_ * H_;
    } else {
        if (t >= S_) return;
        tt = t;
        xb  = x_h + (size_t)tt * F_;  ldx = S_ * F_;  cx = 1;
        Wih = Wih0;  Whh = Whh0;  bias = bias0;  c = c1g;
        hp     = h1buf + (size_t)((tt - 1) & 1) * B_ * H_;
        hn_out = h1buf + (size_t)(tt & 1) * B_ * H_;
    }

    const int thr  = threadIdx.x;
    const int wave = thr >> 6, lane = thr & 63;
    const int quad = lane >> 4, l15 = lane & 15;
    const int hbase = ht * 32;

    // bias folded into accumulator init (col = nt*16 + l15)
    float bv0 = bias[wave * H_ + hbase + l15];
    float bv1 = bias[wave * H_ + hbase + 16 + l15];
    f4 acc[2][2];
    #pragma unroll
    for (int mt = 0; mt < 2; ++mt) {
        acc[mt][0] = (f4){bv0, bv0, bv0, bv0};
        acc[mt][1] = (f4){bv1, bv1, bv1, bv1};
    }

    const int nchunks = cx + 16;            // K = cx*64 + 1024 (l0:17, l1:32)
    const int ghW = wave * 32 + ht;         // packed-W (gate,ht) group
    const int ar  = thr >> 3;               // A staging row 0..31
    const int ak  = (thr & 7) * 8;          // A staging k-offset

    auto loadA = [&](int ck) -> f4 {
        const half_t* Ab; int lda, k0;
        if (ck < cx) { Ab = xb; lda = ldx; k0 = ck * 64; }
        else         { Ab = hp; lda = H_;  k0 = (ck - cx) * 64; }
        return *(const f4*)&Ab[(size_t)(bt * 32 + ar) * lda + k0 + ak];
    };
    auto fetchW = [&](int ck, h8& r0, h8& r1, h8& r2, h8& r3) {
        const half_t* Wb; int ckk, NC;
        if (ck < cx) { Wb = Wih; ckk = ck;      NC = cx; }
        else         { Wb = Whh; ckk = ck - cx; NC = 16; }
        const half_t* base = Wb + ((size_t)(((ghW * NC) + ckk) * 4) * 64 + lane) * 8;
        r0 = *(const h8*)(base + 0 * 512);
        r1 = *(const h8*)(base + 1 * 512);
        r2 = *(const h8*)(base + 2 * 512);
        r3 = *(const h8*)(base + 3 * 512);
    };

    // ---- prologue: window 0 A loads + W chunks 0..2 + tail prefetches ----
    h8 W0a,W0b,W0c,W0d, W1a,W1b,W1c,W1d, W2a,W2b,W2c,W2d, W3a,W3b,W3c,W3d;
    f4 p0, p1, p2, p3, p4, p5, p6, p7;
    p0 = loadA(0); p1 = loadA(1); p2 = loadA(2); p3 = loadA(3);
    p4 = loadA(4); p5 = loadA(5); p6 = loadA(6); p7 = loadA(7);
    fetchW(0, W0a,W0b,W0c,W0d);
    fetchW(1, W1a,W1b,W1c,W1d);
    fetchW(2, W2a,W2b,W2c,W2d);

    // c-state prefetch: this block is the sole writer of its (b,h) slice this
    // phase, so the value read now == value read at epilogue. Hides L2 latency.
    float cpre[4];
    #pragma unroll
    for (int kk = 0; kk < 4; ++kk) {
        int e = thr + kk * 256;
        int b = e >> 5, col = e & 31;
        cpre[kk] = c[(size_t)(bt * 32 + b) * H_ + hbase + col];
    }
    // fcW t-slice prefetch (l1 only): 24x32 f32 = 3/thread, HBM-cold ~900cy,
    // consumed only at the FC tail -> fully hidden under the K-loop.
    float fpre[3] = {0.f, 0.f, 0.f};
    if (l1) {
        const float* fcWt = fcW + (size_t)tt * H_;
        #pragma unroll
        for (int q = 0; q < 3; ++q) {
            int p = thr + q * 256;
            fpre[q] = fcWt[(size_t)(p >> 5) * (S_ * H_) + hbase + (p & 31)];
        }
    }

    *(f4*)&A_s[0 * 2304 + ar * 72 + ak] = p0;
    *(f4*)&A_s[1 * 2304 + ar * 72 + ak] = p1;
    *(f4*)&A_s[2 * 2304 + ar * 72 + ak] = p2;
    *(f4*)&A_s[3 * 2304 + ar * 72 + ak] = p3;
    *(f4*)&A_s[4 * 2304 + ar * 72 + ak] = p4;
    *(f4*)&A_s[5 * 2304 + ar * 72 + ak] = p5;
    *(f4*)&A_s[6 * 2304 + ar * 72 + ak] = p6;
    *(f4*)&A_s[7 * 2304 + ar * 72 + ak] = p7;
    __syncthreads();   // window 0 visible

    for (int s = 0; s < nchunks; s += 8) {
        const int ns  = (nchunks - s < 8) ? (nchunks - s) : 8;   // block-uniform
        int ns2 = nchunks - s - 8; if (ns2 > 8) ns2 = 8;         // next window size
        const int bufo = ((s >> 3) & 1) * 18432;                 // read buffer (halfs)
        const int obuf = 18432 - bufo;                           // write buffer

        // ---- issue NEXT window's A loads; consumed by stores after compute ----
        if (ns2 > 0) p0 = loadA(s + 8 + 0);
        if (ns2 > 1) p1 = loadA(s + 8 + 1);
        if (ns2 > 2) p2 = loadA(s + 8 + 2);
        if (ns2 > 3) p3 = loadA(s + 8 + 3);
        if (ns2 > 4) p4 = loadA(s + 8 + 4);
        if (ns2 > 5) p5 = loadA(s + 8 + 5);
        if (ns2 > 6) p6 = loadA(s + 8 + 6);
        if (ns2 > 7) p7 = loadA(s + 8 + 7);

        // ---- compute ns chunks; W pipeline stays 3 chunks ahead (4 sets,
        //      chunk c uses set c&3; 8%4==0 keeps alignment across windows) ----
        #define STEP(i, C0,C1,C2,C3, N0,N1,N2,N3)                                              \
        if (i < ns) {                                                                          \
            if (s + i + 3 < nchunks) fetchW(s + i + 3, N0, N1, N2, N3);                        \
            h8 a0 = *(const h8*)&A_s[bufo + i * 2304 + (0  + l15) * 72 + 0  + quad * 8];       \
            h8 a1 = *(const h8*)&A_s[bufo + i * 2304 + (16 + l15) * 72 + 0  + quad * 8];       \
            h8 a2 = *(const h8*)&A_s[bufo + i * 2304 + (0  + l15) * 72 + 32 + quad * 8];       \
            h8 a3 = *(const h8*)&A_s[bufo + i * 2304 + (16 + l15) * 72 + 32 + quad * 8];       \
            acc[0][0] = __builtin_amdgcn_mfma_f32_16x16x32_f16(a0, C0, acc[0][0], 0,0,0);      \
            acc[0][1] = __builtin_amdgcn_mfma_f32_16x16x32_f16(a0, C2, acc[0][1], 0,0,0);      \
            acc[1][0] = __builtin_amdgcn_mfma_f32_16x16x32_f16(a1, C0, acc[1][0], 0,0,0);      \
            acc[1][1] = __builtin_amdgcn_mfma_f32_16x16x32_f16(a1, C2, acc[1][1], 0,0,0);      \
            acc[0][0] = __builtin_amdgcn_mfma_f32_16x16x32_f16(a2, C1, acc[0][0], 0,0,0);      \
            acc[0][1] = __builtin_amdgcn_mfma_f32_16x16x32_f16(a2, C3, acc[0][1], 0,0,0);      \
            acc[1][0] = __builtin_amdgcn_mfma_f32_16x16x32_f16(a3, C1, acc[1][0], 0,0,0);      \
            acc[1][1] = __builtin_amdgcn_mfma_f32_16x16x32_f16(a3, C3, acc[1][1], 0,0,0);      \
        }
        STEP(0, W0a,W0b,W0c,W0d,  W3a,W3b,W3c,W3d)
        STEP(1, W1a,W1b,W1c,W1d,  W0a,W0b,W0c,W0d)
        STEP(2, W2a,W2b,W2c,W2d,  W1a,W1b,W1c,W1d)
        STEP(3, W3a,W3b,W3c,W3d,  W2a,W2b,W2c,W2d)
        STEP(4, W0a,W0b,W0c,W0d,  W3a,W3b,W3c,W3d)
        STEP(5, W1a,W1b,W1c,W1d,  W0a,W0b,W0c,W0d)
        STEP(6, W2a,W2b,W2c,W2d,  W1a,W1b,W1c,W1d)
        STEP(7, W3a,W3b,W3c,W3d,  W2a,W2b,W2c,W2d)
        #undef STEP

        // ---- store next window into the other buffer; ONE barrier/window.
        //      Write-buffer's old readers finished before the PREVIOUS
        //      window's barrier, so no pre-store barrier is needed. ----
        if (ns2 > 0) {
            /*always*/      *(f4*)&A_s[obuf + 0 * 2304 + ar * 72 + ak] = p0;
            if (ns2 > 1)    *(f4*)&A_s[obuf + 1 * 2304 + ar * 72 + ak] = p1;
            if (ns2 > 2)    *(f4*)&A_s[obuf + 2 * 2304 + ar * 72 + ak] = p2;
            if (ns2 > 3)    *(f4*)&A_s[obuf + 3 * 2304 + ar * 72 + ak] = p3;
            if (ns2 > 4)    *(f4*)&A_s[obuf + 4 * 2304 + ar * 72 + ak] = p4;
            if (ns2 > 5)    *(f4*)&A_s[obuf + 5 * 2304 + ar * 72 + ak] = p5;
            if (ns2 > 6)    *(f4*)&A_s[obuf + 6 * 2304 + ar * 72 + ak] = p6;
            if (ns2 > 7)    *(f4*)&A_s[obuf + 7 * 2304 + ar * 72 + ak] = p7;
            __syncthreads();   // next window visible
        }
    }

    __syncthreads();   // all waves done reading A windows before LDS reuse

    // scatter gates (C/D layout col=lane&15, row=quad*4+reg)
    #pragma unroll
    for (int mt = 0; mt < 2; ++mt)
        #pragma unroll
        for (int nt = 0; nt < 2; ++nt)
            #pragma unroll
            for (int r = 0; r < 4; ++r)
                gate_s[wave * (32 * 33) + (mt * 16 + quad * 4 + r) * 33 + nt * 16 + l15] = acc[mt][nt][r];
    __syncthreads();

    // cell update: 1024 (b,h) elems, 4/thread; c was prefetched at t0
    #pragma unroll
    for (int kk = 0; kk < 4; ++kk) {
        int e = thr + kk * 256;
        int b = e >> 5, col = e & 31;
        float gi = gate_s[0 * (32 * 33) + b * 33 + col];
        float gf = gate_s[1 * (32 * 33) + b * 33 + col];
        float gg = gate_s[2 * (32 * 33) + b * 33 + col];
        float go = gate_s[3 * (32 * 33) + b * 33 + col];
        float si = 1.f / (1.f + __expf(-gi));
        float sf = 1.f / (1.f + __expf(-gf));
        float so = 1.f / (1.f + __expf(-go));
        float tg = tanhf(gg);
        size_t cidx = (size_t)(bt * 32 + b) * H_ + hbase + col;
        float cn = sf * cpre[kk] + si * tg;
        c[cidx] = cn;
        float hnv = so * tanhf(cn);
        hn_out[cidx] = (half_t)hnv;
        h_s[b * 33 + col] = hnv;
    }

    if (l1) {
        // stage prefetched fcW slice (region disjoint from gate_s/h_s)
        fcw_s[thr]       = fpre[0];
        fcw_s[thr + 256] = fpre[1];
        fcw_s[thr + 512] = fpre[2];
        __syncthreads();
        for (int p = thr; p < 32 * O_; p += 256) {
            int o = p >> 5, bb = p & 31;
            float s2 = 0.f;
            #pragma unroll
            for (int j = 0; j < 32; ++j)
                s2 += h_s[bb * 33 + j] * fcw_s[o * 32 + j];
            out_part[ht * (B_ * O_) + (bt * 32 + bb) * O_ + o] += s2;
        }
    }
}

__global__ void k_final(const float* __restrict__ out_part, const float* __restrict__ fcb,
                        float* __restrict__ out) {
    int i = blockIdx.x * blockDim.x + threadIdx.x;
    if (i >= B_ * O_) return;
    int o = i % O_;
    float s = fcb[o];
    for (int t = 0; t < 32; ++t) s += out_part[t * (B_ * O_) + i];
    out[i] = s;
}

extern "C" void kernel_launch(void* const* d_in, const int* in_sizes, int n_in,
                              void* d_out, int out_size, void* d_ws, size_t ws_size,
                              hipStream_t stream) {
    const float* x    = (const float*)d_in[0];
    const float* Wih0 = (const float*)d_in[1];
    const float* Whh0 = (const float*)d_in[2];
    const float* bih0 = (const float*)d_in[3];
    const float* bhh0 = (const float*)d_in[4];
    const float* Wih1 = (const float*)d_in[5];
    const float* Whh1 = (const float*)d_in[6];
    const float* bih1 = (const float*)d_in[7];
    const float* bhh1 = (const float*)d_in[8];
    const float* fcW  = (const float*)d_in[9];
    const float* fcb  = (const float*)d_in[10];

    char* ws = (char*)d_ws;
    half_t* h1buf  = (half_t*)(ws + OFF_H1);
    half_t* h2buf  = (half_t*)(ws + OFF_H2);
    float*  c1     = (float*)(ws + OFF_C1);
    float*  c2     = (float*)(ws + OFF_C2);
    float*  opart  = (float*)(ws + OFF_OP);
    float*  bias0  = (float*)(ws + OFF_BIAS0);
    float*  bias1  = (float*)(ws + OFF_BIAS1);
    half_t* x_h    = (half_t*)(ws + OFF_XH);
    half_t* wih0_p = (half_t*)(ws + OFF_WIH0);
    half_t* whh0_p = (half_t*)(ws + OFF_WHH0);
    half_t* wih1_p = (half_t*)(ws + OFF_WIH1);
    half_t* whh1_p = (half_t*)(ws + OFF_WHH1);

    // zero states + FC partials (ws poisoned 0xAA before every launch)
    hipMemsetAsync(d_ws, 0, ZBYTES, stream);

    k_bias<<<dim3((G_ + 255) / 256), dim3(256), 0, stream>>>(bih0, bhh0, bih1, bhh1, bias0, bias1);
    k_cvt<<<dim3(2048), dim3(256), 0, stream>>>(x, x_h, B_ * S_ * F_);
    k_pack<<<dim3(128),  dim3(256), 0, stream>>>(Wih0, wih0_p, 1);
    k_pack<<<dim3(2048), dim3(256), 0, stream>>>(Whh0, whh0_p, 16);
    k_pack<<<dim3(2048), dim3(256), 0, stream>>>(Wih1, wih1_p, 16);
    k_pack<<<dim3(2048), dim3(256), 0, stream>>>(Whh1, whh1_p, 16);

    dim3 grid(512), blk(256);
    for (int t = 0; t <= S_; ++t) {
        k_phase<<<grid, blk, 0, stream>>>(t, x_h,
                                          wih0_p, whh0_p, bias0, c1, h1buf,
                                          wih1_p, whh1_p, bias1, c2, h2buf,
                                          fcW, opart);
    }
    k_final<<<dim3((B_ * O_ + 255) / 256), dim3(256), 0, stream>>>(opart, fcb, (float*)d_out);
}

// Round 4
// 9640.137 us; speedup vs baseline: 1.1031x; 1.0319x over previous
//
#include <hip/hip_runtime.h>
#include <hip/hip_fp16.h>

#define B_ 256
#define S_ 512
#define F_ 64
#define H_ 1024
#define O_ 24
#define G_ 4096  // 4*H
#define NT_ 64   // ht' tile count (16-col tiles)

typedef _Float16 half_t;
typedef _Float16 h8 __attribute__((ext_vector_type(8)));
typedef float f4 __attribute__((ext_vector_type(4)));

// ---- workspace layout (bytes) ----
#define OFF_H1 ((size_t)0)                                   // 2*B*H halfs (ping-pong)
#define OFF_H2 (OFF_H1 + (size_t)2*B_*H_*2)
#define OFF_C1 (OFF_H2 + (size_t)2*B_*H_*2)                  // B*H f32
#define OFF_C2 (OFF_C1 + (size_t)B_*H_*4)
#define OFF_OP (OFF_C2 + (size_t)B_*H_*4)                    // out_part [64][B][O] f32
#define ZBYTES (OFF_OP + (size_t)NT_*B_*O_*4)
#define OFF_BIAS0 (ZBYTES)
#define OFF_BIAS1 (OFF_BIAS0 + (size_t)G_*4)
#define OFF_XH    (OFF_BIAS1 + (size_t)G_*4)                 // B*S*F halfs
#define OFF_WIH0  (OFF_XH + (size_t)B_*S_*F_*2)              // packed, G*F halfs
#define OFF_WHH0  (OFF_WIH0 + (size_t)G_*F_*2)               // packed, G*H halfs
#define OFF_WIH1  (OFF_WHH0 + (size_t)G_*H_*2)
#define OFF_WHH1  (OFF_WIH1 + (size_t)G_*H_*2)
#define WS_NEEDED (OFF_WHH1 + (size_t)G_*H_*2)               // ~46 MiB

__global__ void k_bias(const float* __restrict__ bi0, const float* __restrict__ bh0,
                       const float* __restrict__ bi1, const float* __restrict__ bh1,
                       float* __restrict__ bias0, float* __restrict__ bias1) {
    int i = blockIdx.x * blockDim.x + threadIdx.x;
    if (i < G_) { bias0[i] = bi0[i] + bh0[i]; bias1[i] = bi1[i] + bh1[i]; }
}

__global__ void k_cvt(const float* __restrict__ src, half_t* __restrict__ dst, int n) {
    int i = blockIdx.x * blockDim.x + threadIdx.x;
    int stride = gridDim.x * blockDim.x;
    for (; i < n; i += stride) dst[i] = (half_t)src[i];
}

// Pack W [4H, NC*64] f32 -> fp16 MFMA-fragment order:
// dst h8 index i = (((g*32+ht)*NC + ck)*4 + j)*64 + lane, j = colhalf*2 + kshalf
// (N=16 tiles address colhalf via j offset jo=(ht'&1)*2 -- no repack needed)
__global__ void k_pack(const float* __restrict__ src, half_t* __restrict__ dst, int NC) {
    int i = blockIdx.x * blockDim.x + threadIdx.x;
    int total = 32768 * NC;          // 4*32*NC*4*64
    if (i >= total) return;
    int lane = i & 63;
    int j    = (i >> 6) & 3;
    int ck   = (i >> 8) % NC;
    int gh   = i / (256 * NC);       // g*32+ht, 0..127
    int srow = (gh >> 5) * H_ + (gh & 31) * 32 + (j >> 1) * 16 + (lane & 15);
    int scol = ck * 64 + (j & 1) * 32 + (lane >> 4) * 8;
    const float* s = src + (size_t)srow * (NC * 64) + scol;
    h8 v;
    #pragma unroll
    for (int e = 0; e < 8; ++e) v[e] = (half_t)s[e];
    *(h8*)&dst[(size_t)i * 8] = v;
}

// ---------------------------------------------------------------------------
// R2 restructure, 3rd submission (two acquire-level infra failures: error had
// no timing fields at all -> container never acquired; kernel audited
// OOB/race/occupancy-clean 3x). Theory: W L2/L1 streaming bound.
//  * tile 64b x 16h x 4 gates, 512-thr blocks (8 waves: gate=w>>1, mhalf=w&1)
//  * grid 256 = 64 ht' x 4 bt; EVERY block runs layer0 then layer1 part
//    (independent within a phase) -> perfect per-CU balance, 1 block/CU,
//    2 waves/SIMD (same occupancy as before).
//  * M=32->64 halves W bytes served per phase (196->100 MB); wave pair
//    (2g,2g+1) fetches identical W -> L1/MSHR dedupe halves per-CU W demand.
//  * window-4 double-buffered A in the proven 73728B LDS; 3-deep W register
//    pipeline; epilogue c/fcW prefetched at part start (hidden under K-loop).
// ---------------------------------------------------------------------------
__device__ __forceinline__ void run_part(
    const int thr, const int bt, const int htp,
    const int cx, const int nchunks,
    const half_t* __restrict__ xb, const int ldx,
    const half_t* __restrict__ hp,
    const half_t* __restrict__ Wih, const half_t* __restrict__ Whh,
    const float* __restrict__ bias,
    float* __restrict__ c, half_t* __restrict__ hn_out,
    const float* __restrict__ fcWt, float* __restrict__ out_part,
    half_t* A_s, float* gate_s, float* h_s, float* fcw_s,
    const bool do_fc)
{
    const int wave = thr >> 6, lane = thr & 63;
    const int gate = wave >> 1, mh = wave & 1;
    const int quad = lane >> 4, l15 = lane & 15;
    const int ar = thr >> 3;             // A staging row 0..63
    const int ak = (thr & 7) * 8;        // A staging k-offset (halfs)
    const int ghW = gate * 32 + (htp >> 1);
    const int jo  = (htp & 1) * 2;       // fragment col-half select

    float bv = bias[gate * H_ + htp * 16 + l15];
    f4 acc0 = (f4){bv, bv, bv, bv};      // rows mh*32 + 0..15
    f4 acc1 = acc0;                      // rows mh*32 + 16..31

    auto loadA = [&](int ck) -> f4 {
        const half_t* Ab; int lda, k0;
        if (ck < cx) { Ab = xb; lda = ldx; k0 = ck * 64; }
        else         { Ab = hp; lda = H_;  k0 = (ck - cx) * 64; }
        return *(const f4*)&Ab[(size_t)(bt * 64 + ar) * lda + k0 + ak];
    };
    auto fetchW = [&](int ck, h8& r0, h8& r1) {
        const half_t* Wb; int ckk, NC;
        if (ck < cx) { Wb = Wih; ckk = ck;      NC = cx; }
        else         { Wb = Whh; ckk = ck - cx; NC = 16; }
        const half_t* base = Wb + ((size_t)(((ghW * NC) + ckk) * 4 + jo) * 64 + lane) * 8;
        r0 = *(const h8*)(base + 0 * 512);
        r1 = *(const h8*)(base + 1 * 512);
    };

    // ---- prologue: window 0 A loads + W chunks 0..2 ----
    h8 W0a,W0b, W1a,W1b, W2a,W2b, W3a,W3b;
    f4 p0, p1, p2, p3;
    p0 = loadA(0); p1 = loadA(1); p2 = loadA(2); p3 = loadA(3);
    fetchW(0, W0a, W0b);
    fetchW(1, W1a, W1b);
    fetchW(2, W2a, W2b);

    // epilogue prefetches: this block is sole owner of its (b,h) slice this
    // phase, so c read now == c at epilogue; fcW slice is const + HBM-cold.
    const int eb = thr >> 4, ecol = thr & 15;
    const size_t cbase = (size_t)(bt * 64 + eb) * H_ + htp * 16 + ecol;
    float cpre0 = c[cbase];
    float cpre1 = c[cbase + (size_t)32 * H_];
    float fpre = 0.f;
    if (do_fc && thr < 384)
        fpre = fcWt[(size_t)(thr >> 4) * (S_ * H_) + htp * 16 + (thr & 15)];

    *(f4*)&A_s[0 * 4608 + ar * 72 + ak] = p0;
    *(f4*)&A_s[1 * 4608 + ar * 72 + ak] = p1;
    *(f4*)&A_s[2 * 4608 + ar * 72 + ak] = p2;
    *(f4*)&A_s[3 * 4608 + ar * 72 + ak] = p3;
    __syncthreads();   // window 0 visible

    for (int s = 0; s < nchunks; s += 4) {
        const int rem = nchunks - s;
        const int ns = rem < 4 ? rem : 4;                 // block-uniform
        int ns2 = rem - 4; if (ns2 < 0) ns2 = 0; if (ns2 > 4) ns2 = 4;
        const int bufo = ((s >> 2) & 1) * 18432;          // read buffer (halfs)
        const int obuf = 18432 - bufo;                    // write buffer

        // issue NEXT window's A loads (latency hides under compute)
        if (ns2 > 0) p0 = loadA(s + 4);
        if (ns2 > 1) p1 = loadA(s + 5);
        if (ns2 > 2) p2 = loadA(s + 6);
        if (ns2 > 3) p3 = loadA(s + 7);

        // compute ns chunks; W pipeline 3 ahead (4 sets, chunk c -> set c&3)
        #define STEP(i, C0,C1, N0,N1)                                                          \
        if (i < ns) {                                                                          \
            if (s + i + 3 < nchunks) fetchW(s + i + 3, N0, N1);                                \
            h8 a0 = *(const h8*)&A_s[bufo + i * 4608 + (mh * 32 + l15) * 72 + quad * 8];       \
            h8 a1 = *(const h8*)&A_s[bufo + i * 4608 + (mh * 32 + 16 + l15) * 72 + quad * 8];  \
            h8 a2 = *(const h8*)&A_s[bufo + i * 4608 + (mh * 32 + l15) * 72 + 32 + quad * 8];  \
            h8 a3 = *(const h8*)&A_s[bufo + i * 4608 + (mh * 32 + 16 + l15) * 72 + 32 + quad * 8]; \
            acc0 = __builtin_amdgcn_mfma_f32_16x16x32_f16(a0, C0, acc0, 0, 0, 0);              \
            acc1 = __builtin_amdgcn_mfma_f32_16x16x32_f16(a1, C0, acc1, 0, 0, 0);              \
            acc0 = __builtin_amdgcn_mfma_f32_16x16x32_f16(a2, C1, acc0, 0, 0, 0);              \
            acc1 = __builtin_amdgcn_mfma_f32_16x16x32_f16(a3, C1, acc1, 0, 0, 0);              \
        }
        STEP(0, W0a,W0b, W3a,W3b)
        STEP(1, W1a,W1b, W0a,W0b)
        STEP(2, W2a,W2b, W1a,W1b)
        STEP(3, W3a,W3b, W2a,W2b)
        #undef STEP

        // store next window into the other buffer; ONE barrier per window
        if (ns2 > 0) {
            /*always*/       *(f4*)&A_s[obuf + 0 * 4608 + ar * 72 + ak] = p0;
            if (ns2 > 1)     *(f4*)&A_s[obuf + 1 * 4608 + ar * 72 + ak] = p1;
            if (ns2 > 2)     *(f4*)&A_s[obuf + 2 * 4608 + ar * 72 + ak] = p2;
            if (ns2 > 3)     *(f4*)&A_s[obuf + 3 * 4608 + ar * 72 + ak] = p3;
            __syncthreads();
        }
    }
    __syncthreads();   // all waves done with A windows before LDS reuse

    // scatter gates (C/D layout: col=lane&15, row=quad*4+reg)
    #pragma unroll
    for (int r = 0; r < 4; ++r) {
        gate_s[gate * (64 * 17) + (mh * 32 + quad * 4 + r) * 17 + l15]      = acc0[r];
        gate_s[gate * (64 * 17) + (mh * 32 + 16 + quad * 4 + r) * 17 + l15] = acc1[r];
    }
    __syncthreads();

    // cell update: 64x16 = 1024 (b,h) elems, 2/thread; c prefetched at start
    #pragma unroll
    for (int kk = 0; kk < 2; ++kk) {
        int b = eb + kk * 32;
        float gi = gate_s[0 * (64 * 17) + b * 17 + ecol];
        float gf = gate_s[1 * (64 * 17) + b * 17 + ecol];
        float gg = gate_s[2 * (64 * 17) + b * 17 + ecol];
        float go = gate_s[3 * (64 * 17) + b * 17 + ecol];
        float si = 1.f / (1.f + __expf(-gi));
        float sf = 1.f / (1.f + __expf(-gf));
        float so = 1.f / (1.f + __expf(-go));
        float tg = tanhf(gg);
        float cn = sf * (kk ? cpre1 : cpre0) + si * tg;
        size_t cidx = cbase + (size_t)kk * 32 * H_;
        c[cidx] = cn;
        float hnv = so * tanhf(cn);
        hn_out[cidx] = (half_t)hnv;
        if (do_fc) h_s[b * 17 + ecol] = hnv;
    }

    if (do_fc) {
        if (thr < 384) fcw_s[thr] = fpre;   // [24][16] staged from prefetch
        __syncthreads();
        #pragma unroll
        for (int q = 0; q < 3; ++q) {
            int p = thr + q * 512;           // 0..1535 = 64b x 24o
            int o = p >> 6, bb = p & 63;
            float s2 = 0.f;
            #pragma unroll
            for (int j = 0; j < 16; ++j)
                s2 += h_s[bb * 17 + j] * fcw_s[o * 16 + j];
            out_part[(size_t)htp * (B_ * O_) + (bt * 64 + bb) * O_ + o] += s2;
        }
    }
    __syncthreads();   // guard LDS reuse by the next part
}

__global__ __launch_bounds__(512, 2)
void k_phase(int t,
             const half_t* __restrict__ x_h,
             const half_t* __restrict__ Wih0, const half_t* __restrict__ Whh0,
             const float* __restrict__ bias0, float* __restrict__ c1g, half_t* __restrict__ h1buf,
             const half_t* __restrict__ Wih1, const half_t* __restrict__ Whh1,
             const float* __restrict__ bias1, float* __restrict__ c2g, half_t* __restrict__ h2buf,
             const float* __restrict__ fcW, float* __restrict__ out_part)
{
    // window-4 double-buffered A: 2 x [4][64*72] halfs = 73728 B (proven size)
    // epilogue LDS unioned on top (23296 B used)
    __shared__ __align__(16) char smraw[73728];
    half_t* A_s    = (half_t*)smraw;
    float*  gate_s = (float*)smraw;                  // [4][64*17] = 17408 B
    float*  h_s    = (float*)(smraw + 17408);        // [64*17]    =  4352 B
    float*  fcw_s  = (float*)(smraw + 21760);        // [24*16]    =  1536 B

    const int n   = blockIdx.x;
    const int htp = (n & 7) + 8 * ((n >> 3) & 7);    // htp % 8 == n % 8 (XCD-resident W)
    const int bt  = (n >> 6) & 3;
    const int thr = threadIdx.x;

    if (t < S_) {       // layer-0 part: h1(t) from x(t), h1(t-1)
        const int tt = t;
        run_part(thr, bt, htp, /*cx=*/1, /*nchunks=*/17,
                 x_h + (size_t)tt * F_, S_ * F_,
                 h1buf + (size_t)((tt - 1) & 1) * B_ * H_,
                 Wih0, Whh0, bias0, c1g,
                 h1buf + (size_t)(tt & 1) * B_ * H_,
                 nullptr, nullptr,
                 A_s, gate_s, h_s, fcw_s, false);
    }
    if (t > 0) {        // layer-1 part: h2(t-1) from h1(t-1), h2(t-2); + FC tail
        const int tt = t - 1;
        run_part(thr, bt, htp, /*cx=*/16, /*nchunks=*/32,
                 h1buf + (size_t)(tt & 1) * B_ * H_, H_,
                 h2buf + (size_t)((tt - 1) & 1) * B_ * H_,
                 Wih1, Whh1, bias1, c2g,
                 h2buf + (size_t)(tt & 1) * B_ * H_,
                 fcW + (size_t)tt * H_, out_part,
                 A_s, gate_s, h_s, fcw_s, true);
    }
}

__global__ void k_final(const float* __restrict__ out_part, const float* __restrict__ fcb,
                        float* __restrict__ out) {
    int i = blockIdx.x * blockDim.x + threadIdx.x;
    if (i >= B_ * O_) return;
    int o = i % O_;
    float s = fcb[o];
    for (int tl = 0; tl < NT_; ++tl) s += out_part[(size_t)tl * (B_ * O_) + i];
    out[i] = s;
}

extern "C" void kernel_launch(void* const* d_in, const int* in_sizes, int n_in,
                              void* d_out, int out_size, void* d_ws, size_t ws_size,
                              hipStream_t stream) {
    const float* x    = (const float*)d_in[0];
    const float* Wih0 = (const float*)d_in[1];
    const float* Whh0 = (const float*)d_in[2];
    const float* bih0 = (const float*)d_in[3];
    const float* bhh0 = (const float*)d_in[4];
    const float* Wih1 = (const float*)d_in[5];
    const float* Whh1 = (const float*)d_in[6];
    const float* bih1 = (const float*)d_in[7];
    const float* bhh1 = (const float*)d_in[8];
    const float* fcW  = (const float*)d_in[9];
    const float* fcb  = (const float*)d_in[10];

    char* ws = (char*)d_ws;
    half_t* h1buf  = (half_t*)(ws + OFF_H1);
    half_t* h2buf  = (half_t*)(ws + OFF_H2);
    float*  c1     = (float*)(ws + OFF_C1);
    float*  c2     = (float*)(ws + OFF_C2);
    float*  opart  = (float*)(ws + OFF_OP);
    float*  bias0  = (float*)(ws + OFF_BIAS0);
    float*  bias1  = (float*)(ws + OFF_BIAS1);
    half_t* x_h    = (half_t*)(ws + OFF_XH);
    half_t* wih0_p = (half_t*)(ws + OFF_WIH0);
    half_t* whh0_p = (half_t*)(ws + OFF_WHH0);
    half_t* wih1_p = (half_t*)(ws + OFF_WIH1);
    half_t* whh1_p = (half_t*)(ws + OFF_WHH1);

    // zero states + FC partials (ws poisoned 0xAA before every launch)
    hipMemsetAsync(d_ws, 0, ZBYTES, stream);

    k_bias<<<dim3((G_ + 255) / 256), dim3(256), 0, stream>>>(bih0, bhh0, bih1, bhh1, bias0, bias1);
    k_cvt<<<dim3(2048), dim3(256), 0, stream>>>(x, x_h, B_ * S_ * F_);
    k_pack<<<dim3(128),  dim3(256), 0, stream>>>(Wih0, wih0_p, 1);
    k_pack<<<dim3(2048), dim3(256), 0, stream>>>(Whh0, whh0_p, 16);
    k_pack<<<dim3(2048), dim3(256), 0, stream>>>(Wih1, wih1_p, 16);
    k_pack<<<dim3(2048), dim3(256), 0, stream>>>(Whh1, whh1_p, 16);

    dim3 grid(256), blk(512);
    for (int t = 0; t <= S_; ++t) {
        k_phase<<<grid, blk, 0, stream>>>(t, x_h,
                                          wih0_p, whh0_p, bias0, c1, h1buf,
                                          wih1_p, whh1_p, bias1, c2, h2buf,
                                          fcW, opart);
    }
    k_final<<<dim3((B_ * O_ + 255) / 256), dim3(256), 0, stream>>>(opart, fcb, (float*)d_out);
}